// Round 1
// baseline (339.933 us; speedup 1.0000x reference)
//
#include <hip/hip_runtime.h>
#include <math.h>

// Problem constants
#define CC   128         // channels
#define NL   16384       // N * H * W = 4*64*64
#define LHW  4096        // H*W
#define OMW  108         // G*3*K
#define HH   64
#define WW   64

// ---------------------------------------------------------------------------
// Tiled transpose x (N,C,H,W) -> xT (N*HW, C)   [NHWC rows]
// ---------------------------------------------------------------------------
__global__ __launch_bounds__(256) void transpose_x_kernel(
    const float* __restrict__ x, float* __restrict__ xT)
{
    __shared__ float tile[32][33];
    int b   = blockIdx.x;              // 2048 blocks: 128 hw-tiles x 4 c-tiles x 4 n
    int hw0 = (b & 127) << 5;
    int c0  = ((b >> 7) & 3) << 5;
    int n   = b >> 9;
    int tx  = threadIdx.x & 31;
    int ty0 = threadIdx.x >> 5;        // 0..7
    const float* xp = x + ((size_t)(n * CC + c0)) * LHW + hw0;
#pragma unroll
    for (int i = 0; i < 4; i++) {
        int cy = ty0 + i * 8;
        tile[cy][tx] = xp[(size_t)cy * LHW + tx];
    }
    __syncthreads();
    float* op = xT + ((size_t)(n * LHW + hw0)) * CC + c0;
#pragma unroll
    for (int i = 0; i < 4; i++) {
        int ry = ty0 + i * 8;
        op[(size_t)ry * CC + tx] = tile[tx][ry];
    }
}

// Wc (o,c) -> WcT (c,o)
__global__ __launch_bounds__(256) void transpose_wc_kernel(
    const float* __restrict__ Wc, float* __restrict__ WcT)
{
    int idx = blockIdx.x * 256 + threadIdx.x;   // 16384
    int o = idx >> 7, k = idx & 127;
    WcT[k * CC + o] = Wc[idx];
}

__global__ __launch_bounds__(256) void zero_stats_kernel(float* __restrict__ stats)
{
    int i = blockIdx.x * 256 + threadIdx.x;
    if (i < 512) stats[i] = 0.0f;
}

// ---------------------------------------------------------------------------
// GEMM: C(M,NB) = A(M,128) * B(128,NB) (+bias). Optional NCHW scatter-write.
// Block tile 64x128, micro tile 4x8, BK=32, 256 threads.
// ---------------------------------------------------------------------------
template<bool HAS_BIAS, bool OUT_NCHW>
__global__ __launch_bounds__(256) void gemm_kernel(
    const float* __restrict__ A, const float* __restrict__ B,
    const float* __restrict__ bias, float* __restrict__ Cmat, int NB)
{
    const int K = CC;
    const int BM = 64, BN = 128, BK = 32;
    __shared__ float As[BK][BM + 1];    // transposed: As[k][m]
    __shared__ float Bs[BK][BN + 4];

    int tid     = threadIdx.x;
    int block_m = blockIdx.x * BM;
    int row_t   = tid & 15;
    int col_t   = tid >> 4;
    int m0      = row_t * 4;
    int n0      = col_t * 8;

    float acc[4][8];
#pragma unroll
    for (int i = 0; i < 4; i++)
#pragma unroll
        for (int j = 0; j < 8; j++) acc[i][j] = 0.0f;

    for (int k0 = 0; k0 < K; k0 += BK) {
        // A tile: 64x32 floats = 512 float4, 2 per thread
#pragma unroll
        for (int i = 0; i < 2; i++) {
            int g  = tid + i * 256;
            int r  = g >> 3;
            int kq = g & 7;
            const float4 av = *(const float4*)(A + (size_t)(block_m + r) * K + k0 + kq * 4);
            As[kq * 4 + 0][r] = av.x;
            As[kq * 4 + 1][r] = av.y;
            As[kq * 4 + 2][r] = av.z;
            As[kq * 4 + 3][r] = av.w;
        }
        // B tile: 32xNB (pad to 128 with zeros)
#pragma unroll
        for (int i = 0; i < 4; i++) {
            int g  = tid + i * 256;
            int kk = g >> 5;
            int nq = g & 31;
            int nn = nq * 4;
            float4 bv;
            if (nn + 3 < NB) {
                bv = *(const float4*)(B + (size_t)(k0 + kk) * NB + nn);
            } else {
                bv.x = (nn + 0 < NB) ? B[(size_t)(k0 + kk) * NB + nn + 0] : 0.0f;
                bv.y = (nn + 1 < NB) ? B[(size_t)(k0 + kk) * NB + nn + 1] : 0.0f;
                bv.z = (nn + 2 < NB) ? B[(size_t)(k0 + kk) * NB + nn + 2] : 0.0f;
                bv.w = (nn + 3 < NB) ? B[(size_t)(k0 + kk) * NB + nn + 3] : 0.0f;
            }
            *(float4*)(&Bs[kk][nn]) = bv;
        }
        __syncthreads();
#pragma unroll
        for (int k = 0; k < BK; k++) {
            float a[4], b[8];
#pragma unroll
            for (int i = 0; i < 4; i++) a[i] = As[k][m0 + i];
#pragma unroll
            for (int j = 0; j < 8; j++) b[j] = Bs[k][n0 + j];
#pragma unroll
            for (int i = 0; i < 4; i++)
#pragma unroll
                for (int j = 0; j < 8; j++) acc[i][j] += a[i] * b[j];
        }
        __syncthreads();
    }

#pragma unroll
    for (int j = 0; j < 8; j++) {
        int col = n0 + j;
        if (col < NB) {
            float bb = HAS_BIAS ? bias[col] : 0.0f;
#pragma unroll
            for (int i = 0; i < 4; i++) {
                int row = block_m + m0 + i;
                float v = acc[i][j] + bb;
                if (OUT_NCHW) {
                    int n_img = row >> 12;
                    int hw    = row & 4095;
                    Cmat[((size_t)(n_img * CC + col) << 12) + hw] = v;
                } else {
                    Cmat[(size_t)row * NB + col] = v;
                }
            }
        }
    }
}

// ---------------------------------------------------------------------------
// Deformable sampling: out[nl, g*32+c] = sum_k mask * bilinear(value)
// One 32-lane group per (nl,g); 8 units per block.
// ---------------------------------------------------------------------------
__global__ __launch_bounds__(256) void sample_kernel(
    const float* __restrict__ value, const float* __restrict__ om,
    float* __restrict__ out)
{
    int tid  = threadIdx.x;
    int unit = blockIdx.x * 8 + (tid >> 5);  // (nl,g), 65536 units
    int c    = tid & 31;
    int nl   = unit >> 2;
    int g    = unit & 3;
    int n    = nl >> 12;
    int hw   = nl & 4095;
    int h    = hw >> 6;
    int w    = hw & 63;

    const float* omp   = om + (size_t)nl * OMW + g * 27;
    const float* vbase = value + (((size_t)n) << 12) * CC + g * 32 + c;

    float acc = 0.0f;
#pragma unroll
    for (int k = 0; k < 9; k++) {
        float ox = omp[2 * k];
        float oy = omp[2 * k + 1];
        float mk = omp[18 + k];
        float ly = (float)(h + k / 3 - 1) + oy;
        float lx = (float)(w + k % 3 - 1) + ox;
        float y0f = floorf(ly), x0f = floorf(lx);
        float wy = ly - y0f, wx = lx - x0f;
        int y0 = (int)y0f, x0 = (int)x0f;

        float v = 0.0f;
#pragma unroll
        for (int cy = 0; cy < 2; cy++) {
#pragma unroll
            for (int cx = 0; cx < 2; cx++) {
                int yi = y0 + cy, xi = x0 + cx;
                float wgt = (cy ? wy : 1.0f - wy) * (cx ? wx : 1.0f - wx);
                bool valid = (yi >= 0) && (yi < HH) && (xi >= 0) && (xi < WW);
                int yc = min(max(yi, 0), HH - 1);
                int xc = min(max(xi, 0), WW - 1);
                float vv = vbase[(size_t)(yc * WW + xc) * CC];
                v += vv * (valid ? wgt : 0.0f);
            }
        }
        acc += mk * v;
    }
    out[(size_t)nl * CC + g * 32 + c] = acc;
}

// ---------------------------------------------------------------------------
// BN stats: per-channel sum / sumsq over 16384 rows, via per-block partials.
// Grid 128 blocks, each handles 128 rows.
// ---------------------------------------------------------------------------
__global__ __launch_bounds__(256) void bnstats_kernel(
    const float* __restrict__ y, float* __restrict__ stats)
{
    int tid  = threadIdx.x;
    int c    = tid & 127;
    int half = tid >> 7;
    const float* p = y + ((size_t)blockIdx.x * 128) * CC;
    float s = 0.0f, sq = 0.0f;
    for (int r = half; r < 128; r += 2) {
        float v = p[(size_t)r * CC + c];
        s += v;
        sq += v * v;
    }
    __shared__ float ls[256], lq[256];
    ls[tid] = s;
    lq[tid] = sq;
    __syncthreads();
    if (tid < 128) {
        atomicAdd(&stats[c], ls[tid] + ls[tid + 128]);
        atomicAdd(&stats[128 + c], lq[tid] + lq[tid + 128]);
    }
}

template<bool RELU, bool ADD_SC>
__global__ __launch_bounds__(256) void bnapply_kernel(
    const float* __restrict__ y, const float* __restrict__ stats,
    const float* __restrict__ gamma, const float* __restrict__ beta,
    const float* __restrict__ shortcut, float* __restrict__ out)
{
    int idx = blockIdx.x * 256 + threadIdx.x;
    int c   = idx & 127;
    const float inv = 1.0f / 16384.0f;
    float mean = stats[c] * inv;
    float var  = stats[128 + c] * inv - mean * mean;
    float sc   = rsqrtf(var + 1e-5f) * gamma[c];
    float v    = (y[idx] - mean) * sc + beta[c];
    if (RELU) v = fmaxf(v, 0.0f);
    if (ADD_SC) v += shortcut[idx];
    out[idx] = v;
}

// ---------------------------------------------------------------------------
extern "C" void kernel_launch(void* const* d_in, const int* in_sizes, int n_in,
                              void* d_out, int out_size, void* d_ws, size_t ws_size,
                              hipStream_t stream)
{
    const float* x     = (const float*)d_in[0];
    const float* Wv    = (const float*)d_in[1];
    const float* bv    = (const float*)d_in[2];
    const float* Wom   = (const float*)d_in[3];
    const float* bom   = (const float*)d_in[4];
    const float* Wo    = (const float*)d_in[5];
    const float* gamma = (const float*)d_in[6];
    const float* beta  = (const float*)d_in[7];
    const float* Wc    = (const float*)d_in[8];
    float* out = (float*)d_out;

    float* ws    = (float*)d_ws;
    float* xT    = ws;                       // 2097152
    float* val   = xT + (size_t)NL * CC;     // 2097152
    float* omb   = val + (size_t)NL * CC;    // 1769472
    float* sbuf  = omb + (size_t)NL * OMW;   // 2097152
    float* ybuf  = sbuf + (size_t)NL * CC;   // 2097152
    float* t2    = ybuf + (size_t)NL * CC;   // 2097152
    float* WcT   = t2 + (size_t)NL * CC;     // 16384
    float* stats = WcT + CC * CC;            // 512  (stage1: 0..255, stage2: 256..511)

    dim3 b256(256);

    // prep
    transpose_x_kernel<<<2048, b256, 0, stream>>>(x, xT);
    transpose_wc_kernel<<<64, b256, 0, stream>>>(Wc, WcT);
    zero_stats_kernel<<<2, b256, 0, stream>>>(stats);

    // ---- DCN block 1 (input = xT) ----
    gemm_kernel<true, false><<<256, b256, 0, stream>>>(xT, Wv, bv, val, CC);
    gemm_kernel<true, false><<<256, b256, 0, stream>>>(xT, Wom, bom, omb, OMW);
    sample_kernel<<<8192, b256, 0, stream>>>(val, omb, sbuf);
    gemm_kernel<false, false><<<256, b256, 0, stream>>>(sbuf, Wo, nullptr, ybuf, CC);
    bnstats_kernel<<<128, b256, 0, stream>>>(ybuf, stats);
    bnapply_kernel<true, false><<<8192, b256, 0, stream>>>(ybuf, stats, gamma, beta, nullptr, t2);

    // ---- DCN block 2 (input = t2) ----
    gemm_kernel<true, false><<<256, b256, 0, stream>>>(t2, Wv, bv, val, CC);
    gemm_kernel<true, false><<<256, b256, 0, stream>>>(t2, Wom, bom, omb, OMW);
    sample_kernel<<<8192, b256, 0, stream>>>(val, omb, sbuf);
    gemm_kernel<false, false><<<256, b256, 0, stream>>>(sbuf, Wo, nullptr, ybuf, CC);
    bnstats_kernel<<<128, b256, 0, stream>>>(ybuf, stats + 256);
    // bn (no relu) + residual add (xT, NHWC) -> sbuf (free after its GEMM)
    bnapply_kernel<false, true><<<8192, b256, 0, stream>>>(ybuf, stats + 256, gamma, beta, xT, sbuf);

    // final 1x1 conv: out[n,o,h,w] = sum_c t_fin[nl,c] * Wc[o,c]  (B = WcT, NCHW write)
    gemm_kernel<false, true><<<256, b256, 0, stream>>>(sbuf, WcT, nullptr, out, CC);
}

// Round 2
// 216.512 us; speedup vs baseline: 1.5700x; 1.5700x over previous
//
#include <hip/hip_runtime.h>
#include <math.h>

// Problem constants
#define CC   128         // channels
#define NL   16384       // N * H * W = 4*64*64
#define LHW  4096        // H*W
#define OMP  112         // padded om row stride (108 real cols)
#define HH   64
#define WW   64

typedef __attribute__((ext_vector_type(8))) short short8;
typedef __attribute__((ext_vector_type(4))) float f32x4;

__device__ __forceinline__ unsigned short f2bf(float f) {
    union { float f; unsigned u; } v; v.f = f;
    unsigned r = v.u + 0x7fff + ((v.u >> 16) & 1);   // RNE
    return (unsigned short)(r >> 16);
}

// ---------------------------------------------------------------------------
// Weight prep: WvT/WoT (n,k) <- W (k,n) bf16 ; WomT padded to 112 rows ; Wc direct
// ---------------------------------------------------------------------------
__global__ __launch_bounds__(256) void prep_weights_kernel(
    const float* __restrict__ Wv, const float* __restrict__ Wo,
    const float* __restrict__ Wom, const float* __restrict__ Wc,
    unsigned short* __restrict__ WvT, unsigned short* __restrict__ WoT,
    unsigned short* __restrict__ WomT, unsigned short* __restrict__ Wcb)
{
    int i = blockIdx.x * 256 + threadIdx.x;      // 63488 total
    if (i < 16384) {
        int n = i >> 7, k = i & 127;
        WvT[i] = f2bf(Wv[k * CC + n]);
    } else if (i < 32768) {
        int j = i - 16384; int n = j >> 7, k = j & 127;
        WoT[j] = f2bf(Wo[k * CC + n]);
    } else if (i < 47104) {
        int j = i - 32768; int n = j >> 7, k = j & 127;   // n in 0..111
        WomT[j] = (n < 108) ? f2bf(Wom[k * 108 + n]) : (unsigned short)0;
    } else {
        int j = i - 47104;
        Wcb[j] = f2bf(Wc[j]);   // Wc[o][c] already is Bt[n=o][k=c]
    }
}

// ---------------------------------------------------------------------------
// Transpose x (N,C,H,W) -> xT fp32 (residual) + xbf bf16 (GEMM A), NHWC rows
// ---------------------------------------------------------------------------
__global__ __launch_bounds__(256) void transpose_x_kernel(
    const float* __restrict__ x, float* __restrict__ xT,
    unsigned short* __restrict__ xbf)
{
    __shared__ float tile[32][33];
    int b   = blockIdx.x;              // 2048 blocks
    int hw0 = (b & 127) << 5;
    int c0  = ((b >> 7) & 3) << 5;
    int n   = b >> 9;
    int tx  = threadIdx.x & 31;
    int ty0 = threadIdx.x >> 5;
    const float* xp = x + ((size_t)(n * CC + c0)) * LHW + hw0;
#pragma unroll
    for (int i = 0; i < 4; i++) {
        int cy = ty0 + i * 8;
        tile[cy][tx] = xp[(size_t)cy * LHW + tx];
    }
    __syncthreads();
    size_t base = ((size_t)(n * LHW + hw0)) * CC + c0;
#pragma unroll
    for (int i = 0; i < 4; i++) {
        int ry = ty0 + i * 8;
        float v = tile[tx][ry];
        xT[base + (size_t)ry * CC + tx] = v;
        xbf[base + (size_t)ry * CC + tx] = f2bf(v);
    }
}

__global__ __launch_bounds__(256) void zero_stats_kernel(float* __restrict__ stats)
{
    int i = blockIdx.x * 256 + threadIdx.x;
    if (i < 512) stats[i] = 0.0f;
}

// ---------------------------------------------------------------------------
// MFMA GEMM, N=128, K=128 (single shot). Block: 64 rows, 4 waves in 2x2.
// A: bf16 [M][128] row-major.  Bt: bf16 [128][128] = B^T (Bt[n][k]).
// OUT_MODE: 0 = fp32 [M][128], 1 = bf16 [M][128], 2 = fp32 NCHW scatter.
// ---------------------------------------------------------------------------
template<bool HAS_BIAS, int OUT_MODE>
__global__ __launch_bounds__(256) void gemm128_kernel(
    const unsigned short* __restrict__ A, const unsigned short* __restrict__ Bt,
    const float* __restrict__ bias, void* __restrict__ Cout)
{
    __shared__ unsigned short As[64 * 136];     // row stride 136 bf16 (272B): conflict-safe
    __shared__ unsigned short Bs[128 * 136];

    int tid = threadIdx.x;
    int block_m = blockIdx.x * 64;

    // stage A: 64x128 bf16 = 1024 chunks of 8
#pragma unroll
    for (int i = 0; i < 4; i++) {
        int id = tid + i * 256;
        int r = id >> 4, kc = id & 15;
        float4 v = *(const float4*)(A + (size_t)(block_m + r) * CC + kc * 8);
        *(float4*)(&As[r * 136 + kc * 8]) = v;
    }
    // stage B: 128x128 bf16 = 2048 chunks
#pragma unroll
    for (int i = 0; i < 8; i++) {
        int id = tid + i * 256;
        int r = id >> 4, kc = id & 15;
        float4 v = *(const float4*)(Bt + (size_t)r * CC + kc * 8);
        *(float4*)(&Bs[r * 136 + kc * 8]) = v;
    }
    __syncthreads();

    int w  = tid >> 6;
    int l  = tid & 63;
    int wm = w & 1, wn = w >> 1;
    int lr = l & 15, lk = l >> 4;

    f32x4 acc[2][4];
#pragma unroll
    for (int mt = 0; mt < 2; mt++)
#pragma unroll
        for (int nt = 0; nt < 4; nt++) acc[mt][nt] = (f32x4){0.f, 0.f, 0.f, 0.f};

#pragma unroll
    for (int kk = 0; kk < 4; kk++) {
        short8 a[2], b[4];
#pragma unroll
        for (int mt = 0; mt < 2; mt++) {
            int row = wm * 32 + mt * 16 + lr;
            a[mt] = *(const short8*)(&As[row * 136 + kk * 32 + lk * 8]);
        }
#pragma unroll
        for (int nt = 0; nt < 4; nt++) {
            int row = wn * 64 + nt * 16 + lr;
            b[nt] = *(const short8*)(&Bs[row * 136 + kk * 32 + lk * 8]);
        }
#pragma unroll
        for (int mt = 0; mt < 2; mt++)
#pragma unroll
            for (int nt = 0; nt < 4; nt++)
                acc[mt][nt] = __builtin_amdgcn_mfma_f32_16x16x32_bf16(
                    a[mt], b[nt], acc[mt][nt], 0, 0, 0);
    }

    if (OUT_MODE == 0 || OUT_MODE == 1) {
#pragma unroll
        for (int mt = 0; mt < 2; mt++) {
            int row0 = block_m + wm * 32 + mt * 16 + lk * 4;
#pragma unroll
            for (int nt = 0; nt < 4; nt++) {
                int col = wn * 64 + nt * 16 + lr;
                float bb = HAS_BIAS ? bias[col] : 0.0f;
#pragma unroll
                for (int r = 0; r < 4; r++) {
                    float v = acc[mt][nt][r] + bb;
                    if (OUT_MODE == 0)
                        ((float*)Cout)[(size_t)(row0 + r) * CC + col] = v;
                    else
                        ((unsigned short*)Cout)[(size_t)(row0 + r) * CC + col] = f2bf(v);
                }
            }
        }
    } else {
        // NCHW scatter: transpose 64(hw) x 128(o) tile via LDS (reuse Bs as fp32[128][68])
        __syncthreads();
        float* T = (float*)Bs;                  // 128*68*4 = 34816 B == sizeof(Bs)
#pragma unroll
        for (int mt = 0; mt < 2; mt++) {
            int rloc = wm * 32 + mt * 16 + lk * 4;
#pragma unroll
            for (int nt = 0; nt < 4; nt++) {
                int col = wn * 64 + nt * 16 + lr;
#pragma unroll
                for (int r = 0; r < 4; r++)
                    T[col * 68 + rloc + r] = acc[mt][nt][r];
            }
        }
        __syncthreads();
        int n_img = block_m >> 12;
        int hw0   = block_m & 4095;
        int o = tid >> 1, half = tid & 1;
        float* op = (float*)Cout + (((size_t)(n_img * CC + o)) << 12) + hw0 + half * 32;
#pragma unroll
        for (int i = 0; i < 8; i++) {
            float4 v = *(const float4*)(&T[o * 68 + half * 32 + i * 4]);
            *(float4*)(op + i * 4) = v;
        }
    }
}

// ---------------------------------------------------------------------------
// MFMA GEMM, N=112 (108 real + 4 zero-pad), for offset/mask projection.
// Block: 64 rows, 4 waves each 16 rows x 112 cols. Out fp32 stride 112.
// ---------------------------------------------------------------------------
__global__ __launch_bounds__(256) void gemm112_kernel(
    const unsigned short* __restrict__ A, const unsigned short* __restrict__ Bt,
    const float* __restrict__ bias, float* __restrict__ Cout)
{
    __shared__ unsigned short As[64 * 136];
    __shared__ unsigned short Bs[112 * 136];

    int tid = threadIdx.x;
    int block_m = blockIdx.x * 64;

#pragma unroll
    for (int i = 0; i < 4; i++) {
        int id = tid + i * 256;
        int r = id >> 4, kc = id & 15;
        float4 v = *(const float4*)(A + (size_t)(block_m + r) * CC + kc * 8);
        *(float4*)(&As[r * 136 + kc * 8]) = v;
    }
#pragma unroll
    for (int i = 0; i < 7; i++) {
        int id = tid + i * 256;                 // 1792 chunks
        int r = id >> 4, kc = id & 15;
        float4 v = *(const float4*)(Bt + (size_t)r * CC + kc * 8);
        *(float4*)(&Bs[r * 136 + kc * 8]) = v;
    }
    __syncthreads();

    int w  = tid >> 6;
    int l  = tid & 63;
    int lr = l & 15, lk = l >> 4;

    f32x4 acc[7];
#pragma unroll
    for (int nt = 0; nt < 7; nt++) acc[nt] = (f32x4){0.f, 0.f, 0.f, 0.f};

#pragma unroll
    for (int kk = 0; kk < 4; kk++) {
        int arow = w * 16 + lr;
        short8 a = *(const short8*)(&As[arow * 136 + kk * 32 + lk * 8]);
#pragma unroll
        for (int nt = 0; nt < 7; nt++) {
            int row = nt * 16 + lr;
            short8 b = *(const short8*)(&Bs[row * 136 + kk * 32 + lk * 8]);
            acc[nt] = __builtin_amdgcn_mfma_f32_16x16x32_bf16(a, b, acc[nt], 0, 0, 0);
        }
    }

    int row0 = block_m + w * 16 + lk * 4;
#pragma unroll
    for (int nt = 0; nt < 7; nt++) {
        int col = nt * 16 + lr;
        float bval = (col < 108) ? bias[col] : 0.0f;   // pad cols: zero B rows + zero bias
#pragma unroll
        for (int r = 0; r < 4; r++)
            Cout[(size_t)(row0 + r) * OMP + col] = acc[nt][r] + bval;
    }
}

// ---------------------------------------------------------------------------
// Deformable sampling: out_bf16[nl, g*32+c] = sum_k mask * bilinear(value)
// ---------------------------------------------------------------------------
__global__ __launch_bounds__(256) void sample_kernel(
    const float* __restrict__ value, const float* __restrict__ om,
    unsigned short* __restrict__ out)
{
    int tid  = threadIdx.x;
    int unit = blockIdx.x * 8 + (tid >> 5);
    int c    = tid & 31;
    int nl   = unit >> 2;
    int g    = unit & 3;
    int n    = nl >> 12;
    int hw   = nl & 4095;
    int h    = hw >> 6;
    int w    = hw & 63;

    const float* omp   = om + (size_t)nl * OMP + g * 27;
    const float* vbase = value + (((size_t)n) << 12) * CC + g * 32 + c;

    float acc = 0.0f;
#pragma unroll
    for (int k = 0; k < 9; k++) {
        float ox = omp[2 * k];
        float oy = omp[2 * k + 1];
        float mk = omp[18 + k];
        float ly = (float)(h + k / 3 - 1) + oy;
        float lx = (float)(w + k % 3 - 1) + ox;
        float y0f = floorf(ly), x0f = floorf(lx);
        float wy = ly - y0f, wx = lx - x0f;
        int y0 = (int)y0f, x0 = (int)x0f;

        float v = 0.0f;
#pragma unroll
        for (int cy = 0; cy < 2; cy++) {
#pragma unroll
            for (int cx = 0; cx < 2; cx++) {
                int yi = y0 + cy, xi = x0 + cx;
                float wgt = (cy ? wy : 1.0f - wy) * (cx ? wx : 1.0f - wx);
                bool valid = (yi >= 0) && (yi < HH) && (xi >= 0) && (xi < WW);
                int yc = min(max(yi, 0), HH - 1);
                int xc = min(max(xi, 0), WW - 1);
                float vv = vbase[(size_t)(yc * WW + xc) * CC];
                v += vv * (valid ? wgt : 0.0f);
            }
        }
        acc += mk * v;
    }
    out[(size_t)nl * CC + g * 32 + c] = f2bf(acc);
}

// ---------------------------------------------------------------------------
// BN stats: per-channel sum / sumsq
// ---------------------------------------------------------------------------
__global__ __launch_bounds__(256) void bnstats_kernel(
    const float* __restrict__ y, float* __restrict__ stats)
{
    int tid  = threadIdx.x;
    int c    = tid & 127;
    int half = tid >> 7;
    const float* p = y + ((size_t)blockIdx.x * 128) * CC;
    float s = 0.0f, sq = 0.0f;
    for (int r = half; r < 128; r += 2) {
        float v = p[(size_t)r * CC + c];
        s += v;
        sq += v * v;
    }
    __shared__ float ls[256], lq[256];
    ls[tid] = s;
    lq[tid] = sq;
    __syncthreads();
    if (tid < 128) {
        atomicAdd(&stats[c], ls[tid] + ls[tid + 128]);
        atomicAdd(&stats[128 + c], lq[tid] + lq[tid + 128]);
    }
}

// BN apply (+optional ReLU, +optional residual), writes bf16 for next GEMM A
template<bool RELU, bool ADD_SC>
__global__ __launch_bounds__(256) void bnapply_kernel(
    const float* __restrict__ y, const float* __restrict__ stats,
    const float* __restrict__ gamma, const float* __restrict__ beta,
    const float* __restrict__ shortcut, unsigned short* __restrict__ out)
{
    int idx = blockIdx.x * 256 + threadIdx.x;
    int c   = idx & 127;
    const float inv = 1.0f / 16384.0f;
    float mean = stats[c] * inv;
    float var  = stats[128 + c] * inv - mean * mean;
    float sc   = rsqrtf(var + 1e-5f) * gamma[c];
    float v    = (y[idx] - mean) * sc + beta[c];
    if (RELU) v = fmaxf(v, 0.0f);
    if (ADD_SC) v += shortcut[idx];
    out[idx] = f2bf(v);
}

// ---------------------------------------------------------------------------
extern "C" void kernel_launch(void* const* d_in, const int* in_sizes, int n_in,
                              void* d_out, int out_size, void* d_ws, size_t ws_size,
                              hipStream_t stream)
{
    const float* x     = (const float*)d_in[0];
    const float* Wv    = (const float*)d_in[1];
    const float* bv    = (const float*)d_in[2];
    const float* Wom   = (const float*)d_in[3];
    const float* bom   = (const float*)d_in[4];
    const float* Wo    = (const float*)d_in[5];
    const float* gamma = (const float*)d_in[6];
    const float* beta  = (const float*)d_in[7];
    const float* Wc    = (const float*)d_in[8];
    float* out = (float*)d_out;

    char* ws = (char*)d_ws;
    float*          xT    = (float*)ws;                       ws += 8388608;
    unsigned short* xbf   = (unsigned short*)ws;              ws += 4194304;
    float*          val   = (float*)ws;                       ws += 8388608;
    float*          omb   = (float*)ws;                       ws += 7340032;
    unsigned short* sbuf  = (unsigned short*)ws;              ws += 4194304;
    float*          ybuf  = (float*)ws;                       ws += 8388608;
    unsigned short* t2    = (unsigned short*)ws;              ws += 4194304;
    unsigned short* fin   = (unsigned short*)ws;              ws += 4194304;
    unsigned short* WvT   = (unsigned short*)ws;              ws += 32768;
    unsigned short* WoT   = (unsigned short*)ws;              ws += 32768;
    unsigned short* WomT  = (unsigned short*)ws;              ws += 28672;
    unsigned short* Wcb   = (unsigned short*)ws;              ws += 32768;
    float*          stats = (float*)ws;                       ws += 2048;

    dim3 b256(256);

    prep_weights_kernel<<<248, b256, 0, stream>>>(Wv, Wo, Wom, Wc, WvT, WoT, WomT, Wcb);
    transpose_x_kernel<<<2048, b256, 0, stream>>>(x, xT, xbf);
    zero_stats_kernel<<<2, b256, 0, stream>>>(stats);

    // ---- DCN block 1 ----
    gemm128_kernel<true, 0><<<256, b256, 0, stream>>>(xbf, WvT, bv, val);
    gemm112_kernel<<<256, b256, 0, stream>>>(xbf, WomT, bom, omb);
    sample_kernel<<<8192, b256, 0, stream>>>(val, omb, sbuf);
    gemm128_kernel<false, 0><<<256, b256, 0, stream>>>(sbuf, WoT, nullptr, ybuf);
    bnstats_kernel<<<128, b256, 0, stream>>>(ybuf, stats);
    bnapply_kernel<true, false><<<8192, b256, 0, stream>>>(ybuf, stats, gamma, beta, nullptr, t2);

    // ---- DCN block 2 ----
    gemm128_kernel<true, 0><<<256, b256, 0, stream>>>(t2, WvT, bv, val);
    gemm112_kernel<<<256, b256, 0, stream>>>(t2, WomT, bom, omb);
    sample_kernel<<<8192, b256, 0, stream>>>(val, omb, sbuf);
    gemm128_kernel<false, 0><<<256, b256, 0, stream>>>(sbuf, WoT, nullptr, ybuf);
    bnstats_kernel<<<128, b256, 0, stream>>>(ybuf, stats + 256);
    bnapply_kernel<false, true><<<8192, b256, 0, stream>>>(ybuf, stats + 256, gamma, beta, xT, fin);

    // final 1x1 conv, NCHW output
    gemm128_kernel<false, 2><<<256, b256, 0, stream>>>(fin, Wcb, nullptr, out);
}

// Round 4
// 157.531 us; speedup vs baseline: 2.1579x; 1.3744x over previous
//
#include <hip/hip_runtime.h>
#include <math.h>

// Problem constants
#define CC   128         // channels
#define NL   16384       // N * H * W = 4*64*64
#define LHW  4096        // H*W
#define OMP  112         // padded om row stride (108 real cols)
#define HH   64
#define WW   64

typedef __attribute__((ext_vector_type(8))) short short8;
typedef __attribute__((ext_vector_type(4))) float f32x4;

__device__ __forceinline__ unsigned short f2bf(float f) {
    union { float f; unsigned u; } v; v.f = f;
    unsigned r = v.u + 0x7fff + ((v.u >> 16) & 1);   // RNE
    return (unsigned short)(r >> 16);
}
__device__ __forceinline__ float bf2f(unsigned short u) {
    union { unsigned u; float f; } v; v.u = ((unsigned)u) << 16;
    return v.f;
}

// ---------------------------------------------------------------------------
// Weight prep + stats zero.
// Wcomb[240][128] bf16: rows 0..127 = Wv^T, rows 128..239 = Wom^T (pad 108->112)
// WoT[128][128] = Wo^T ; Wcb[128][128] = Wc (already Bt layout: [o][c]).
// ---------------------------------------------------------------------------
__global__ __launch_bounds__(256) void prep_kernel(
    const float* __restrict__ Wv, const float* __restrict__ Wom,
    const float* __restrict__ Wo, const float* __restrict__ Wc,
    unsigned short* __restrict__ Wcomb, unsigned short* __restrict__ WoT,
    unsigned short* __restrict__ Wcb, float* __restrict__ stats)
{
    int tid = threadIdx.x;
    if (blockIdx.x == 0) {               // zero 512 stats floats
        stats[tid] = 0.0f;
        stats[256 + tid] = 0.0f;
    }
    int i = blockIdx.x * 256 + tid;      // 63488 total
    if (i < 16384) {
        int n = i >> 7, k = i & 127;
        Wcomb[i] = f2bf(Wv[k * CC + n]);
    } else if (i < 30720) {
        int j = i - 16384; int n = j >> 7, k = j & 127;   // n in 0..111
        Wcomb[16384 + j] = (n < 108) ? f2bf(Wom[k * 108 + n]) : (unsigned short)0;
    } else if (i < 47104) {
        int j = i - 30720; int n = j >> 7, k = j & 127;
        WoT[j] = f2bf(Wo[k * CC + n]);
    } else if (i < 63488) {
        int j = i - 47104;
        Wcb[j] = f2bf(Wc[j]);
    }
}

// ---------------------------------------------------------------------------
// Fused value+om GEMM: [M=16384 x N=240 x K=128].
// IN_MODE 0: A = x in NCHW (transpose in LDS staging).
// IN_MODE 1: A = bn_relu(ybuf) (NHWC), stats/gamma/beta applied in staging.
// Outputs: val bf16 [M][128] (+bv), omb fp32 [M][112] (+bom, cols<108).
// 4 waves; wave w computes rows w*16..w*16+15 x all 240 cols (15 frags).
// ---------------------------------------------------------------------------
template<int IN_MODE>
__global__ __launch_bounds__(256) void gemm_vom_kernel(
    const float* __restrict__ Ain, const unsigned short* __restrict__ Wcomb,
    const float* __restrict__ bv, const float* __restrict__ bom,
    const float* __restrict__ stats, const float* __restrict__ gamma,
    const float* __restrict__ beta,
    unsigned short* __restrict__ val, float* __restrict__ omb)
{
    __shared__ unsigned short As[64 * 136];
    __shared__ unsigned short Bs[240 * 136];
    __shared__ float bnsc[128], bnsh[128];

    int tid = threadIdx.x;
    int block_m = blockIdx.x * 64;

    if (IN_MODE == 1 && tid < 128) {
        const float inv = 1.0f / 16384.0f;
        float mean = stats[tid] * inv;
        float var  = stats[128 + tid] * inv - mean * mean;
        float sc   = rsqrtf(var + 1e-5f) * gamma[tid];
        bnsc[tid] = sc;
        bnsh[tid] = beta[tid] - mean * sc;
    }

    // stage B: 240 rows x 128 bf16 = 3840 chunks of 8  (15 x 256, exact)
#pragma unroll
    for (int i = 0; i < 15; i++) {
        int id = tid + i * 256;
        int r = id >> 4, kc = id & 15;
        float4 v = *(const float4*)(Wcomb + (size_t)r * CC + kc * 8);
        *(float4*)(&Bs[r * 136 + kc * 8]) = v;
    }

    if (IN_MODE == 0) {
        // A from x NCHW: 128 channels x 16 float4 along hw
        int n   = block_m >> 12;
        int hw0 = block_m & 4095;
#pragma unroll
        for (int i = 0; i < 8; i++) {
            int id = tid + i * 256;          // 0..2047
            int c  = id >> 4, j4 = id & 15;
            float4 v = *(const float4*)(Ain + (((size_t)(n * CC + c)) << 12) + hw0 + j4 * 4);
            As[(j4 * 4 + 0) * 136 + c] = f2bf(v.x);
            As[(j4 * 4 + 1) * 136 + c] = f2bf(v.y);
            As[(j4 * 4 + 2) * 136 + c] = f2bf(v.z);
            As[(j4 * 4 + 3) * 136 + c] = f2bf(v.w);
        }
    } else {
        __syncthreads();                     // bnsc/bnsh ready
#pragma unroll
        for (int i = 0; i < 8; i++) {
            int id = tid + i * 256;          // 0..2047
            int r  = id >> 5, c4 = id & 31;
            float4 v = *(const float4*)(Ain + (size_t)(block_m + r) * CC + c4 * 4);
            int c = c4 * 4;
            float a0 = fmaxf(v.x * bnsc[c + 0] + bnsh[c + 0], 0.0f);
            float a1 = fmaxf(v.y * bnsc[c + 1] + bnsh[c + 1], 0.0f);
            float a2 = fmaxf(v.z * bnsc[c + 2] + bnsh[c + 2], 0.0f);
            float a3 = fmaxf(v.w * bnsc[c + 3] + bnsh[c + 3], 0.0f);
            As[r * 136 + c + 0] = f2bf(a0);
            As[r * 136 + c + 1] = f2bf(a1);
            As[r * 136 + c + 2] = f2bf(a2);
            As[r * 136 + c + 3] = f2bf(a3);
        }
    }
    __syncthreads();

    int w  = tid >> 6;
    int l  = tid & 63;
    int lr = l & 15, lk = l >> 4;

    f32x4 acc[15];
#pragma unroll
    for (int nt = 0; nt < 15; nt++) acc[nt] = (f32x4){0.f, 0.f, 0.f, 0.f};

#pragma unroll
    for (int kk = 0; kk < 4; kk++) {
        short8 a = *(const short8*)(&As[(w * 16 + lr) * 136 + kk * 32 + lk * 8]);
#pragma unroll
        for (int nt = 0; nt < 15; nt++) {
            short8 b = *(const short8*)(&Bs[(nt * 16 + lr) * 136 + kk * 32 + lk * 8]);
            acc[nt] = __builtin_amdgcn_mfma_f32_16x16x32_bf16(a, b, acc[nt], 0, 0, 0);
        }
    }

    int row0 = block_m + w * 16 + lk * 4;
#pragma unroll
    for (int nt = 0; nt < 8; nt++) {
        int col = nt * 16 + lr;
        float bb = bv[col];
#pragma unroll
        for (int r = 0; r < 4; r++)
            val[(size_t)(row0 + r) * CC + col] = f2bf(acc[nt][r] + bb);
    }
#pragma unroll
    for (int nt = 8; nt < 15; nt++) {
        int col = (nt - 8) * 16 + lr;        // 0..111
        float bb = (col < 108) ? bom[col] : 0.0f;
#pragma unroll
        for (int r = 0; r < 4; r++)
            omb[(size_t)(row0 + r) * OMP + col] = acc[nt][r] + bb;
    }
}

// ---------------------------------------------------------------------------
// Deformable sampling (bf16 value): 16 lanes per (nl,g) unit, 2 channels/lane.
// ---------------------------------------------------------------------------
__global__ __launch_bounds__(256) void sample_kernel(
    const unsigned short* __restrict__ val, const float* __restrict__ omb,
    unsigned int* __restrict__ sbuf)
{
    int tid    = threadIdx.x;
    int gid    = blockIdx.x * 256 + tid;
    int unit   = gid >> 4;                   // 65536 units
    int lane16 = gid & 15;
    int nl = unit >> 2;
    int g  = unit & 3;
    int n  = nl >> 12;
    int hw = nl & 4095;
    int h  = hw >> 6;
    int w  = hw & 63;

    const float* omp = omb + (size_t)nl * OMP + g * 27;
    const unsigned short* vb = val + (((size_t)n) << 19) + g * 32 + lane16 * 2;

    float acc0 = 0.0f, acc1 = 0.0f;
#pragma unroll
    for (int k = 0; k < 9; k++) {
        float ox = omp[2 * k];
        float oy = omp[2 * k + 1];
        float mk = omp[18 + k];
        float ly = (float)(h + k / 3 - 1) + oy;
        float lx = (float)(w + k % 3 - 1) + ox;
        float y0f = floorf(ly), x0f = floorf(lx);
        float wy = ly - y0f, wx = lx - x0f;
        int y0 = (int)y0f, x0 = (int)x0f;

        float v0 = 0.0f, v1 = 0.0f;
#pragma unroll
        for (int cy = 0; cy < 2; cy++) {
#pragma unroll
            for (int cx = 0; cx < 2; cx++) {
                int yi = y0 + cy, xi = x0 + cx;
                float wgt = (cy ? wy : 1.0f - wy) * (cx ? wx : 1.0f - wx);
                bool valid = (yi >= 0) && (yi < HH) && (xi >= 0) && (xi < WW);
                wgt = valid ? wgt : 0.0f;
                int yc = min(max(yi, 0), HH - 1);
                int xc = min(max(xi, 0), WW - 1);
                unsigned int pv = *(const unsigned int*)(vb + (size_t)(yc * WW + xc) * CC);
                v0 += bf2f((unsigned short)(pv & 0xffff)) * wgt;
                v1 += bf2f((unsigned short)(pv >> 16)) * wgt;
            }
        }
        acc0 += mk * v0;
        acc1 += mk * v1;
    }
    unsigned int packed = (unsigned int)f2bf(acc0) | ((unsigned int)f2bf(acc1) << 16);
    sbuf[(size_t)nl * 64 + g * 16 + lane16] = packed;
}

// ---------------------------------------------------------------------------
// Wo GEMM + fused BN-stats: ybuf = sbuf @ Wo ; stats[c] += sum, stats[128+c] += sumsq
// 2x2 wave grid, 64-row tile.
// ---------------------------------------------------------------------------
__global__ __launch_bounds__(256) void gemm_o_bn_kernel(
    const unsigned short* __restrict__ A, const unsigned short* __restrict__ Bt,
    float* __restrict__ ybuf, float* __restrict__ stats)
{
    __shared__ unsigned short As[64 * 136];
    __shared__ unsigned short Bs[128 * 136];
    __shared__ float lstat[256];

    int tid = threadIdx.x;
    int block_m = blockIdx.x * 64;
    lstat[tid] = 0.0f;

#pragma unroll
    for (int i = 0; i < 4; i++) {
        int id = tid + i * 256;
        int r = id >> 4, kc = id & 15;
        float4 v = *(const float4*)(A + (size_t)(block_m + r) * CC + kc * 8);
        *(float4*)(&As[r * 136 + kc * 8]) = v;
    }
#pragma unroll
    for (int i = 0; i < 8; i++) {
        int id = tid + i * 256;
        int r = id >> 4, kc = id & 15;
        float4 v = *(const float4*)(Bt + (size_t)r * CC + kc * 8);
        *(float4*)(&Bs[r * 136 + kc * 8]) = v;
    }
    __syncthreads();

    int w  = tid >> 6;
    int l  = tid & 63;
    int wm = w & 1, wn = w >> 1;
    int lr = l & 15, lk = l >> 4;

    f32x4 acc[2][4];
#pragma unroll
    for (int mt = 0; mt < 2; mt++)
#pragma unroll
        for (int nt = 0; nt < 4; nt++) acc[mt][nt] = (f32x4){0.f, 0.f, 0.f, 0.f};

#pragma unroll
    for (int kk = 0; kk < 4; kk++) {
        short8 a[2], b[4];
#pragma unroll
        for (int mt = 0; mt < 2; mt++)
            a[mt] = *(const short8*)(&As[(wm * 32 + mt * 16 + lr) * 136 + kk * 32 + lk * 8]);
#pragma unroll
        for (int nt = 0; nt < 4; nt++)
            b[nt] = *(const short8*)(&Bs[(wn * 64 + nt * 16 + lr) * 136 + kk * 32 + lk * 8]);
#pragma unroll
        for (int mt = 0; mt < 2; mt++)
#pragma unroll
            for (int nt = 0; nt < 4; nt++)
                acc[mt][nt] = __builtin_amdgcn_mfma_f32_16x16x32_bf16(
                    a[mt], b[nt], acc[mt][nt], 0, 0, 0);
    }

    // write + per-lane stats
#pragma unroll
    for (int nt = 0; nt < 4; nt++) {
        int col = wn * 64 + nt * 16 + lr;
        float s = 0.0f, sq = 0.0f;
#pragma unroll
        for (int mt = 0; mt < 2; mt++) {
            int row0 = block_m + wm * 32 + mt * 16 + lk * 4;
#pragma unroll
            for (int r = 0; r < 4; r++) {
                float v = acc[mt][nt][r];
                ybuf[(size_t)(row0 + r) * CC + col] = v;
                s += v;
                sq += v * v;
            }
        }
        atomicAdd(&lstat[col], s);
        atomicAdd(&lstat[128 + col], sq);
    }
    __syncthreads();
    if (tid < 128) {
        atomicAdd(&stats[tid], lstat[tid]);
        atomicAdd(&stats[128 + tid], lstat[128 + tid]);
    }
}

// ---------------------------------------------------------------------------
// Final GEMM: A = bn(ybuf) + x_residual(NCHW), B = Wc; out NCHW fp32.
// ---------------------------------------------------------------------------
__global__ __launch_bounds__(256) void gemm_final_kernel(
    const float* __restrict__ ybuf, const float* __restrict__ x,
    const unsigned short* __restrict__ Bt, const float* __restrict__ stats,
    const float* __restrict__ gamma, const float* __restrict__ beta,
    float* __restrict__ out)
{
    __shared__ unsigned short As[64 * 136];
    __shared__ unsigned short Bs[128 * 136];
    __shared__ float Xs[64 * 132];
    __shared__ float bnsc[128], bnsh[128];

    int tid = threadIdx.x;
    int block_m = blockIdx.x * 64;
    int n   = block_m >> 12;
    int hw0 = block_m & 4095;

    if (tid < 128) {
        const float inv = 1.0f / 16384.0f;
        float mean = stats[tid] * inv;
        float var  = stats[128 + tid] * inv - mean * mean;
        float sc   = rsqrtf(var + 1e-5f) * gamma[tid];
        bnsc[tid] = sc;
        bnsh[tid] = beta[tid] - mean * sc;
    }

    // stage x residual (NCHW -> LDS transpose, fp32)
#pragma unroll
    for (int i = 0; i < 8; i++) {
        int id = tid + i * 256;
        int c  = id >> 4, j4 = id & 15;
        float4 v = *(const float4*)(x + (((size_t)(n * CC + c)) << 12) + hw0 + j4 * 4);
        Xs[(j4 * 4 + 0) * 132 + c] = v.x;
        Xs[(j4 * 4 + 1) * 132 + c] = v.y;
        Xs[(j4 * 4 + 2) * 132 + c] = v.z;
        Xs[(j4 * 4 + 3) * 132 + c] = v.w;
    }
    // stage B
#pragma unroll
    for (int i = 0; i < 8; i++) {
        int id = tid + i * 256;
        int r = id >> 4, kc = id & 15;
        float4 v = *(const float4*)(Bt + (size_t)r * CC + kc * 8);
        *(float4*)(&Bs[r * 136 + kc * 8]) = v;
    }
    __syncthreads();

    // stage A = bn(ybuf) + Xs
#pragma unroll
    for (int i = 0; i < 8; i++) {
        int id = tid + i * 256;
        int r  = id >> 5, c4 = id & 31;
        float4 v = *(const float4*)(ybuf + (size_t)(block_m + r) * CC + c4 * 4);
        int c = c4 * 4;
        float a0 = v.x * bnsc[c + 0] + bnsh[c + 0] + Xs[r * 132 + c + 0];
        float a1 = v.y * bnsc[c + 1] + bnsh[c + 1] + Xs[r * 132 + c + 1];
        float a2 = v.z * bnsc[c + 2] + bnsh[c + 2] + Xs[r * 132 + c + 2];
        float a3 = v.w * bnsc[c + 3] + bnsh[c + 3] + Xs[r * 132 + c + 3];
        As[r * 136 + c + 0] = f2bf(a0);
        As[r * 136 + c + 1] = f2bf(a1);
        As[r * 136 + c + 2] = f2bf(a2);
        As[r * 136 + c + 3] = f2bf(a3);
    }
    __syncthreads();

    int w  = tid >> 6;
    int l  = tid & 63;
    int wm = w & 1, wn = w >> 1;
    int lr = l & 15, lk = l >> 4;

    f32x4 acc[2][4];
#pragma unroll
    for (int mt = 0; mt < 2; mt++)
#pragma unroll
        for (int nt = 0; nt < 4; nt++) acc[mt][nt] = (f32x4){0.f, 0.f, 0.f, 0.f};

#pragma unroll
    for (int kk = 0; kk < 4; kk++) {
        short8 a[2], b[4];
#pragma unroll
        for (int mt = 0; mt < 2; mt++)
            a[mt] = *(const short8*)(&As[(wm * 32 + mt * 16 + lr) * 136 + kk * 32 + lk * 8]);
#pragma unroll
        for (int nt = 0; nt < 4; nt++)
            b[nt] = *(const short8*)(&Bs[(wn * 64 + nt * 16 + lr) * 136 + kk * 32 + lk * 8]);
#pragma unroll
        for (int mt = 0; mt < 2; mt++)
#pragma unroll
            for (int nt = 0; nt < 4; nt++)
                acc[mt][nt] = __builtin_amdgcn_mfma_f32_16x16x32_bf16(
                    a[mt], b[nt], acc[mt][nt], 0, 0, 0);
    }

    // NCHW scatter via LDS transpose (reuse Bs as float[128][68])
    __syncthreads();
    float* T = (float*)Bs;
#pragma unroll
    for (int mt = 0; mt < 2; mt++) {
        int rloc = wm * 32 + mt * 16 + lk * 4;
#pragma unroll
        for (int nt = 0; nt < 4; nt++) {
            int col = wn * 64 + nt * 16 + lr;
#pragma unroll
            for (int r = 0; r < 4; r++)
                T[col * 68 + rloc + r] = acc[mt][nt][r];
        }
    }
    __syncthreads();
    int o = tid >> 1, half = tid & 1;
    float* op = out + (((size_t)(n * CC + o)) << 12) + hw0 + half * 32;
#pragma unroll
    for (int i = 0; i < 8; i++) {
        float4 v = *(const float4*)(&T[o * 68 + half * 32 + i * 4]);
        *(float4*)(op + i * 4) = v;
    }
}

// ---------------------------------------------------------------------------
extern "C" void kernel_launch(void* const* d_in, const int* in_sizes, int n_in,
                              void* d_out, int out_size, void* d_ws, size_t ws_size,
                              hipStream_t stream)
{
    const float* x     = (const float*)d_in[0];
    const float* Wv    = (const float*)d_in[1];
    const float* bv    = (const float*)d_in[2];
    const float* Wom   = (const float*)d_in[3];
    const float* bom   = (const float*)d_in[4];
    const float* Wo    = (const float*)d_in[5];
    const float* gamma = (const float*)d_in[6];
    const float* beta  = (const float*)d_in[7];
    const float* Wc    = (const float*)d_in[8];
    float* out = (float*)d_out;

    char* ws = (char*)d_ws;
    unsigned short* val   = (unsigned short*)ws;   ws += (size_t)NL * CC * 2;    // 4 MB
    float*          omb   = (float*)ws;            ws += (size_t)NL * OMP * 4;   // 7.34 MB
    unsigned int*   sbuf  = (unsigned int*)ws;     ws += (size_t)NL * CC * 2;    // 4 MB
    float*          ybuf  = (float*)ws;            ws += (size_t)NL * CC * 4;    // 8 MB
    unsigned short* Wcomb = (unsigned short*)ws;   ws += 240 * 128 * 2;
    unsigned short* WoT   = (unsigned short*)ws;   ws += 128 * 128 * 2;
    unsigned short* Wcb   = (unsigned short*)ws;   ws += 128 * 128 * 2;
    float*          stats = (float*)ws;            ws += 2048;

    dim3 b256(256);

    prep_kernel<<<248, b256, 0, stream>>>(Wv, Wom, Wo, Wc, Wcomb, WoT, Wcb, stats);

    // ---- DCN block 1 ----
    gemm_vom_kernel<0><<<256, b256, 0, stream>>>(x, Wcomb, bv, bom,
                                                 nullptr, nullptr, nullptr, val, omb);
    sample_kernel<<<4096, b256, 0, stream>>>(val, omb, sbuf);
    gemm_o_bn_kernel<<<256, b256, 0, stream>>>((const unsigned short*)sbuf, WoT, ybuf, stats);

    // ---- DCN block 2 (bn+relu fused into A-staging) ----
    gemm_vom_kernel<1><<<256, b256, 0, stream>>>(ybuf, Wcomb, bv, bom,
                                                 stats, gamma, beta, val, omb);
    sample_kernel<<<4096, b256, 0, stream>>>(val, omb, sbuf);
    gemm_o_bn_kernel<<<256, b256, 0, stream>>>((const unsigned short*)sbuf, WoT, ybuf, stats + 256);

    // ---- final: bn2 + residual + 1x1 conv, NCHW out ----
    gemm_final_kernel<<<256, b256, 0, stream>>>(ybuf, x, Wcb, stats + 256, gamma, beta, out);
}